// Round 1
// baseline (193.739 us; speedup 1.0000x reference)
//
#include <hip/hip_runtime.h>

// FullGRUODECell_Autonomous_fine — MI355X (gfx950)
//
// dh = (1-z)*(u-h);  z = sigmoid(h@Whz^T + hz);  u = tanh((r*h)@Whh^T);
// r = sigmoid(h@Whr^T);  hz[b,i] = sum_{j,k} h[b,j] h[b,k] Wfine[i*256+j,k]
//
// The bilinear term is a GEMM: hz = G @ Wf^T with G[b, j*256+k]=h[b,j]h[b,k]
// and Wf = Wfine reinterpreted as [256][65536] (flat layouts coincide).
// K1: Wfine f32 -> W2t fp16 in 16KB LDS-image blocks (32 jk per block,
//     layout [n][slot^(n&3)][8]) + h -> fp16.
// K2: MFMA fp16 GEMM, BM=256 x BN=256, K-chunked 64 ways -> 256 wgs,
//     A generated from h (LDS, XOR-swizzled), B via global_load_lds(16B),
//     fp16 partials [64][1024][256] in ws.
// K3a: rlin/zlin (fp32 VALU), writes rh and zlin.
// K3b: ulin + partial reduction + elementwise epilogue -> d_out (f32).

typedef _Float16 f16;
typedef _Float16 f16x8 __attribute__((ext_vector_type(8)));
typedef _Float16 f16x4 __attribute__((ext_vector_type(4)));
typedef float f32x4 __attribute__((ext_vector_type(4)));

__device__ __forceinline__ void gld_lds16(const f16* gp, f16* lp) {
  __builtin_amdgcn_global_load_lds(
      (const __attribute__((address_space(1))) unsigned int*)(const void*)gp,
      (__attribute__((address_space(3))) unsigned int*)(void*)lp, 16, 0, 0);
}

// ---------------- K1: convert Wfine -> W2t (fp16, block layout) and h -> fp16
__global__ __launch_bounds__(256) void k_convert(
    const float* __restrict__ Wf, const float* __restrict__ h,
    f16* __restrict__ W2t, f16* __restrict__ hh) {
  const int gtid = blockIdx.x * 256 + threadIdx.x;
  const int w = gtid >> 6;
  const int l = gtid & 63;
  if (w < 65536) {
    const int n = w >> 8;          // output row of Wf view [256][65536]
    const int c = w & 255;         // 256-wide jk chunk
    const int jk = c * 256 + l * 4;
    float4 v = *(const float4*)(Wf + ((size_t)n << 16) + jk);
    f16x4 o;
    o[0] = (f16)v.x; o[1] = (f16)v.y; o[2] = (f16)v.z; o[3] = (f16)v.w;
    const int blk = jk >> 5;            // 32-jk block
    const int s = (jk >> 3) & 3;        // source 16B slot within 64B row
    const int e0 = jk & 7;              // 0 or 4
    const size_t out = ((size_t)blk << 13) + (n << 5) + (((s ^ (n & 3)) << 3) | e0);
    *(f16x4*)(W2t + out) = o;
  } else {
    const int hw = w - 65536;           // 0..1023
    const int idx = hw * 256 + l * 4;
    float4 v = *(const float4*)(h + idx);
    f16x4 o;
    o[0] = (f16)v.x; o[1] = (f16)v.y; o[2] = (f16)v.z; o[3] = (f16)v.w;
    *(f16x4*)(hh + idx) = o;
  }
}

// ---------------- K2: big MFMA GEMM, partial over K-chunks
__global__ __launch_bounds__(512, 1) void k_gemm(
    const f16* __restrict__ hh, const f16* __restrict__ W2t,
    f16* __restrict__ part) {
  __shared__ __align__(16) f16 h_lds[65536];    // 128 KiB: [256 b][32 slot][8]
  __shared__ __align__(16) f16 B_lds[2][8192];  // 2 x 16 KiB: [n][slot'][8]
  const int tid = threadIdx.x;
  const int mt = blockIdx.x & 3;   // 4 m-tiles of 256 rows
  const int kc = blockIdx.x >> 2;  // 64 K-chunks of 1024 (= 4 j values)
  const int wid = tid >> 6;
  const int l = tid & 63;
  const int lg = l >> 4;           // 0..3 k-group
  const int lr = l & 15;
  const int wm = wid >> 2;         // 0..1 (128-row half)
  const int wn = wid & 3;          // 0..3 (64-col quarter)
  const int aswz = lr & 7;         // == b&7 for all this lane's A rows
  const int bsl = (lg ^ (lr & 3)) << 3;  // == swizzled B slot offset (halfs)

  // stage h tile rows [mt*256, +256), XOR-swizzled slots
  #pragma unroll
  for (int q = 0; q < 16; ++q) {
    const int sl = q * 512 + tid;          // 0..8191
    const int b = sl >> 5, slot = sl & 31;
    f16x8 v = *(const f16x8*)(hh + ((mt * 256 + b) << 8) + (slot << 3));
    *(f16x8*)(h_lds + (b << 8) + ((slot ^ (b & 7)) << 3)) = v;
  }
  const int blk0 = kc * 32;
  {  // prefetch B block 0 (16 KiB linear copy; swizzle pre-baked by K1)
    const f16* g = W2t + ((size_t)blk0 << 13);
    gld_lds16(g + (wid * 2 + 0) * 512 + l * 8, &B_lds[0][(wid * 2 + 0) * 512]);
    gld_lds16(g + (wid * 2 + 1) * 512 + l * 8, &B_lds[0][(wid * 2 + 1) * 512]);
  }

  int brow[8], ncol[4];
  #pragma unroll
  for (int mi = 0; mi < 8; ++mi) brow[mi] = wm * 128 + mi * 16 + lr;
  #pragma unroll
  for (int ni = 0; ni < 4; ++ni) ncol[ni] = wn * 64 + ni * 16 + lr;

  f32x4 acc[8][4];
  #pragma unroll
  for (int mi = 0; mi < 8; ++mi)
    #pragma unroll
    for (int ni = 0; ni < 4; ++ni)
      acc[mi][ni] = f32x4{0.f, 0.f, 0.f, 0.f};

  __syncthreads();

  for (int jj = 0; jj < 4; ++jj) {
    const int j = kc * 4 + jj;
    const int joff = (((j >> 3) ^ aswz) << 3) + (j & 7);
    f16 hj[8];
    #pragma unroll
    for (int mi = 0; mi < 8; ++mi) hj[mi] = h_lds[(brow[mi] << 8) + joff];
    #pragma unroll
    for (int ks = 0; ks < 8; ++ks) {
      const int buf = ks & 1;           // (jj*8+ks)&1 == ks&1
      const int stp = jj * 8 + ks;
      if (stp < 31) {                   // prefetch next 16 KiB B block
        const f16* g = W2t + ((size_t)(blk0 + stp + 1) << 13);
        gld_lds16(g + (wid * 2 + 0) * 512 + l * 8, &B_lds[buf ^ 1][(wid * 2 + 0) * 512]);
        gld_lds16(g + (wid * 2 + 1) * 512 + l * 8, &B_lds[buf ^ 1][(wid * 2 + 1) * 512]);
      }
      const int ksl = ((ks * 4 + lg) ^ aswz) << 3;  // h slot offset (halfs)
      f16x8 afr[8];
      #pragma unroll
      for (int mi = 0; mi < 8; ++mi) {
        f16x8 hk = *(const f16x8*)(h_lds + (brow[mi] << 8) + ksl);
        afr[mi] = hk * hj[mi];          // G[b, j*256+k] = h[b,j]*h[b,k]
      }
      f16x8 bfr[4];
      #pragma unroll
      for (int ni = 0; ni < 4; ++ni)
        bfr[ni] = *(const f16x8*)(&B_lds[buf][(ncol[ni] << 5) + bsl]);
      #pragma unroll
      for (int mi = 0; mi < 8; ++mi)
        #pragma unroll
        for (int ni = 0; ni < 4; ++ni)
          acc[mi][ni] = __builtin_amdgcn_mfma_f32_16x16x32_f16(
              afr[mi], bfr[ni], acc[mi][ni], 0, 0, 0);
      __syncthreads();
    }
  }

  // write fp16 partial tile: part[kc][mt*256 + row][col]
  f16* pout = part + ((size_t)kc << 18) + (mt << 16);
  #pragma unroll
  for (int mi = 0; mi < 8; ++mi) {
    #pragma unroll
    for (int r = 0; r < 4; ++r) {
      const int b = wm * 128 + mi * 16 + lg * 4 + r;  // C row = (l>>4)*4 + reg
      #pragma unroll
      for (int ni = 0; ni < 4; ++ni)
        pout[(b << 8) + wn * 64 + ni * 16 + lr] = (f16)acc[mi][ni][r];  // col = l&15
    }
  }
}

// ---------------- K3a: rlin/zlin small GEMMs (fp32), writes rh and zlin
__global__ __launch_bounds__(256) void k_rz(
    const float* __restrict__ h, const float* __restrict__ Whr,
    const float* __restrict__ Whz, float* __restrict__ rh,
    float* __restrict__ zlin) {
  __shared__ float hs[1024];
  const int t = threadIdx.x;
  const int b0 = blockIdx.x << 2;  // 4 batch rows per wg
  #pragma unroll
  for (int q = 0; q < 4; ++q) hs[(q << 8) + t] = h[((b0 + q) << 8) + t];
  __syncthreads();
  float ar[4] = {0.f, 0.f, 0.f, 0.f}, az[4] = {0.f, 0.f, 0.f, 0.f};
  const float* wr = Whr + t * 256;
  const float* wz = Whz + t * 256;
  for (int k = 0; k < 256; k += 4) {
    float4 a = *(const float4*)(wr + k);
    float4 c = *(const float4*)(wz + k);
    #pragma unroll
    for (int q = 0; q < 4; ++q) {
      const float* hp = hs + (q << 8) + k;
      ar[q] = fmaf(a.x, hp[0], fmaf(a.y, hp[1], fmaf(a.z, hp[2], fmaf(a.w, hp[3], ar[q]))));
      az[q] = fmaf(c.x, hp[0], fmaf(c.y, hp[1], fmaf(c.z, hp[2], fmaf(c.w, hp[3], az[q]))));
    }
  }
  #pragma unroll
  for (int q = 0; q < 4; ++q) {
    const int idx = ((b0 + q) << 8) + t;
    const float r = 1.f / (1.f + __expf(-ar[q]));
    rh[idx] = r * h[idx];
    zlin[idx] = az[q];
  }
}

// ---------------- K3b: ulin GEMM + hz reduction + epilogue
__global__ __launch_bounds__(256) void k_final(
    const float* __restrict__ h, const float* __restrict__ Whh,
    const float* __restrict__ rh, const float* __restrict__ zlin,
    const f16* __restrict__ part, float* __restrict__ out) {
  __shared__ float hs[1024];
  const int t = threadIdx.x;
  const int b0 = blockIdx.x << 2;
  #pragma unroll
  for (int q = 0; q < 4; ++q) hs[(q << 8) + t] = rh[((b0 + q) << 8) + t];
  __syncthreads();
  float au[4] = {0.f, 0.f, 0.f, 0.f};
  const float* wh = Whh + t * 256;
  for (int k = 0; k < 256; k += 4) {
    float4 a = *(const float4*)(wh + k);
    #pragma unroll
    for (int q = 0; q < 4; ++q) {
      const float* hp = hs + (q << 8) + k;
      au[q] = fmaf(a.x, hp[0], fmaf(a.y, hp[1], fmaf(a.z, hp[2], fmaf(a.w, hp[3], au[q]))));
    }
  }
  #pragma unroll
  for (int q = 0; q < 4; ++q) {
    const int idx = ((b0 + q) << 8) + t;
    float hz = 0.f;
    for (int kc = 0; kc < 64; ++kc) hz += (float)part[((size_t)kc << 18) + idx];
    const float z = 1.f / (1.f + __expf(-(zlin[idx] + hz)));
    const float u = tanhf(au[q]);
    out[idx] = (1.f - z) * (u - h[idx]);
  }
}

extern "C" void kernel_launch(void* const* d_in, const int* in_sizes, int n_in,
                              void* d_out, int out_size, void* d_ws, size_t ws_size,
                              hipStream_t stream) {
  const float* h   = (const float*)d_in[1];
  const float* Whr = (const float*)d_in[2];
  const float* Whz = (const float*)d_in[3];
  const float* Whh = (const float*)d_in[4];
  const float* Wf  = (const float*)d_in[5];
  float* out = (float*)d_out;
  char* ws = (char*)d_ws;

  // ws layout (bytes): total ~66.5 MB
  f16*   hh   = (f16*)(ws);                           // 512 KiB
  f16*   W2t  = (f16*)(ws + (1u << 19));              // 32 MiB
  f16*   part = (f16*)(ws + (1u << 19) + (1u << 25)); // 32 MiB (64 x 1024 x 256)
  float* rh   = (float*)(ws + (1u << 19) + (1u << 25) + (1u << 25));             // 1 MiB
  float* zlin = (float*)(ws + (1u << 19) + (1u << 25) + (1u << 25) + (1u << 20)); // 1 MiB

  k_convert<<<dim3(16640), dim3(256), 0, stream>>>(Wf, h, W2t, hh);
  k_gemm<<<dim3(256), dim3(512), 0, stream>>>(hh, W2t, part);
  k_rz<<<dim3(256), dim3(256), 0, stream>>>(h, Whr, Whz, rh, zlin);
  k_final<<<dim3(256), dim3(256), 0, stream>>>(h, Whh, rh, zlin, part, out);
}

// Round 4
// 189.232 us; speedup vs baseline: 1.0238x; 1.0238x over previous
//
#include <hip/hip_runtime.h>

// FullGRUODECell_Autonomous_fine — MI355X (gfx950)
//
// dh = (1-z)*(u-h);  z = sigmoid(h@Whz^T + hz);  u = tanh((r*h)@Whh^T);
// r = sigmoid(h@Whr^T);  hz[b,i] = sum_{j,k} h[b,j] h[b,k] Wfine[i*256+j,k]
//
// hz is a GEMM: hz = G @ Wf^T with G[b, j*256+k]=h[b,j]h[b,k], Wf = Wfine
// viewed [256][65536] (flat layouts coincide).
// K1 k_convert: Wfine f32 -> W2t fp16 [2048 blocks][256 n][32 jk] + h -> fp16.
// K2 k_gemm: MFMA fp16, 256x256 tile, 64 K-chunks x 4 m-tiles (XCD-colocated),
//    per-step 16KB A-window (generated source h) + 16KB B-block staged via
//    global_load_lds, depth-3 pipeline with counted vmcnt + raw s_barrier.
// K3 k_post: fused r/z/u gates + hz partial reduction + epilogue.

typedef _Float16 f16;
typedef _Float16 f16x8 __attribute__((ext_vector_type(8)));
typedef _Float16 f16x4 __attribute__((ext_vector_type(4)));
typedef float f32x4 __attribute__((ext_vector_type(4)));

__device__ __forceinline__ void gld_lds16(const f16* gp, f16* lp) {
  __builtin_amdgcn_global_load_lds(
      (const __attribute__((address_space(1))) unsigned int*)(const void*)gp,
      (__attribute__((address_space(3))) unsigned int*)(void*)lp, 16, 0, 0);
}

// ---------------- K1: Wfine -> W2t fp16 blocked, h -> fp16 (all linear)
__global__ __launch_bounds__(256) void k_convert(
    const float* __restrict__ Wf, const float* __restrict__ h,
    f16* __restrict__ W2t, f16* __restrict__ hh) {
  const int gtid = blockIdx.x * 256 + threadIdx.x;
  const int w = gtid >> 6;
  const int l = gtid & 63;
  if (w < 65536) {
    const int b = w >> 5;               // jk-block 0..2047
    const int n = ((w & 31) << 3) + (l >> 3);  // output row 0..255
    const int e = (l & 7) << 2;         // half-offset in block 0..28
    float4 v = *(const float4*)(Wf + (size_t)n * 65536 + b * 32 + e);
    f16x4 o;
    o[0] = (f16)v.x; o[1] = (f16)v.y; o[2] = (f16)v.z; o[3] = (f16)v.w;
    *(f16x4*)(W2t + (size_t)b * 8192 + n * 32 + e) = o;   // 1KB/wave contiguous
  } else {
    const int hw = w - 65536;           // 0..1023
    const int idx = hw * 256 + l * 4;
    float4 v = *(const float4*)(h + idx);
    f16x4 o;
    o[0] = (f16)v.x; o[1] = (f16)v.y; o[2] = (f16)v.z; o[3] = (f16)v.w;
    *(f16x4*)(hh + idx) = o;
  }
}

// ---------------- K2: MFMA GEMM, depth-3 counted-vmcnt pipeline
__global__ __launch_bounds__(512, 1) void k_gemm(
    const f16* __restrict__ hh, const f16* __restrict__ W2t,
    f16* __restrict__ part) {
  __shared__ __align__(16) f16 Abuf[3][8192];   // 3 x 16KB: [row 0..255][32]
  __shared__ __align__(16) f16 Bbuf[3][8192];   // 3 x 16KB: [col 0..255][32]
  __shared__ __align__(8)  f16 hj_lds[1024];    // [row][4 j]
  const int bid = blockIdx.x;
  // XCD colocate: phys bid = xcd + 8*(slot*4+mt); kc = xcd + 8*slot
  const int kc = (bid & 7) + ((bid >> 5) << 3);
  const int mt = (bid >> 3) & 3;
  const int tid = threadIdx.x;
  const int wid = tid >> 6;
  const int l = tid & 63;
  const int lg = l >> 4, lr = l & 15;
  const int wm = wid >> 2, wn = wid & 3;

  if (tid < 256) {  // h[row][j] for this kc's 4 j-values
    f16x4 hv = *(const f16x4*)(hh + (mt * 256 + tid) * 256 + kc * 4);
    *(f16x4*)(hj_lds + tid * 4) = hv;
  }

  const int c0 = wid * 2;  // this wave's two 16-row staging chunks
  const f16* asrc0 = hh + (size_t)(mt * 256 + c0 * 16 + (l >> 2)) * 256 + (l & 3) * 8;
  const f16* asrc1 = asrc0 + (size_t)16 * 256;
  const f16* bsrc0 = W2t + (size_t)(kc * 32) * 8192 + (size_t)(c0 * 16 + (l >> 2)) * 32 + (l & 3) * 8;
  const f16* bsrc1 = bsrc0 + 16 * 32;

  f32x4 acc[8][4];
  #pragma unroll
  for (int mi = 0; mi < 8; ++mi)
    #pragma unroll
    for (int ni = 0; ni < 4; ++ni)
      acc[mi][ni] = f32x4{0.f, 0.f, 0.f, 0.f};

  auto issue = [&](int n, int b3) {
    gld_lds16(asrc0 + (n & 7) * 32, &Abuf[b3][(c0 + 0) * 512]);   // A k-window cycles mod 8
    gld_lds16(asrc1 + (n & 7) * 32, &Abuf[b3][(c0 + 1) * 512]);
    gld_lds16(bsrc0 + (size_t)n * 8192, &Bbuf[b3][(c0 + 0) * 512]);
    gld_lds16(bsrc1 + (size_t)n * 8192, &Bbuf[b3][(c0 + 1) * 512]);
  };
  issue(0, 0);
  issue(1, 1);
  __syncthreads();  // hj visible; prologue loads drained (one-time cost)

  f16 hjv[8];
  #pragma unroll
  for (int n = 0; n < 32; ++n) {
    // wait: step n's 4 loads done; step n+1's 4 may remain in flight
    if (n < 31) asm volatile("s_waitcnt vmcnt(4)" ::: "memory");
    else        asm volatile("s_waitcnt vmcnt(0)" ::: "memory");
    __builtin_amdgcn_s_barrier();
    if (n + 2 < 32) issue(n + 2, (n + 2) % 3);  // buf(n+2)=buf(n-1): readers done pre-barrier
    if ((n & 7) == 0) {
      const int jj = n >> 3;
      #pragma unroll
      for (int mi = 0; mi < 8; ++mi)
        hjv[mi] = hj_lds[(wm * 128 + mi * 16 + lr) * 4 + jj];
    }
    const int buf = n % 3;
    f16x8 afr[8], bfr[4];
    #pragma unroll
    for (int mi = 0; mi < 8; ++mi) {
      f16x8 av = *(const f16x8*)(&Abuf[buf][(wm * 128 + mi * 16 + lr) * 32 + lg * 8]);
      afr[mi] = av * hjv[mi];           // G[b,jk] = h[b,k]*h[b,j]
    }
    #pragma unroll
    for (int ni = 0; ni < 4; ++ni)
      bfr[ni] = *(const f16x8*)(&Bbuf[buf][(wn * 64 + ni * 16 + lr) * 32 + lg * 8]);
    __builtin_amdgcn_s_setprio(1);
    #pragma unroll
    for (int mi = 0; mi < 8; ++mi)
      #pragma unroll
      for (int ni = 0; ni < 4; ++ni)
        acc[mi][ni] = __builtin_amdgcn_mfma_f32_16x16x32_f16(
            afr[mi], bfr[ni], acc[mi][ni], 0, 0, 0);
    __builtin_amdgcn_s_setprio(0);
  }

  // fp16 partial tile: part[kc][mt*256 + row][col]
  f16* pout = part + ((size_t)kc << 18) + (mt << 16);
  #pragma unroll
  for (int mi = 0; mi < 8; ++mi) {
    #pragma unroll
    for (int r = 0; r < 4; ++r) {
      const int b = wm * 128 + mi * 16 + lg * 4 + r;  // C row = (l>>4)*4 + reg
      #pragma unroll
      for (int ni = 0; ni < 4; ++ni)
        pout[(b << 8) + wn * 64 + ni * 16 + lr] = (f16)acc[mi][ni][r];  // col = l&15
    }
  }
}

// ---------------- K3: fused gates + hz reduction + epilogue
__global__ __launch_bounds__(256) void k_post(
    const float* __restrict__ h, const float* __restrict__ Whr,
    const float* __restrict__ Whz, const float* __restrict__ Whh,
    const f16* __restrict__ part, float* __restrict__ out) {
  __shared__ float hs[4][256];
  __shared__ float rhs[4][256];
  __shared__ float hzs[4][256];
  const int t = threadIdx.x;
  const int b0 = blockIdx.x << 2;  // 4 batch rows per wg
  {  // stage h: 4 rows x 256 = 256 float4, one per thread
    const int row = t >> 6, col = (t & 63) << 2;
    *(float4*)(&hs[row][col]) = *(const float4*)(h + (b0 + row) * 256 + col);
  }
  {  // hz partial reduction: vectorized f16x4 loads
    const int row = t >> 6, c4 = (t & 63) << 2;
    float a0 = 0.f, a1 = 0.f, a2 = 0.f, a3 = 0.f;
    const f16* p = part + (b0 + row) * 256 + c4;
    for (int kc = 0; kc < 64; ++kc) {
      f16x4 v = *(const f16x4*)(p + ((size_t)kc << 18));
      a0 += (float)v[0]; a1 += (float)v[1]; a2 += (float)v[2]; a3 += (float)v[3];
    }
    hzs[row][c4] = a0; hzs[row][c4 + 1] = a1;
    hzs[row][c4 + 2] = a2; hzs[row][c4 + 3] = a3;
  }
  __syncthreads();
  // r/z gates: thread t <-> output col t, 4 rows
  float az[4];
  {
    float ar[4] = {0.f, 0.f, 0.f, 0.f};
    az[0] = az[1] = az[2] = az[3] = 0.f;
    const float* wr = Whr + t * 256;
    const float* wz = Whz + t * 256;
    for (int k = 0; k < 256; k += 4) {
      float4 a = *(const float4*)(wr + k);
      float4 c = *(const float4*)(wz + k);
      #pragma unroll
      for (int q = 0; q < 4; ++q) {
        const float* hp = &hs[q][k];
        ar[q] = fmaf(a.x, hp[0], fmaf(a.y, hp[1], fmaf(a.z, hp[2], fmaf(a.w, hp[3], ar[q]))));
        az[q] = fmaf(c.x, hp[0], fmaf(c.y, hp[1], fmaf(c.z, hp[2], fmaf(c.w, hp[3], az[q]))));
      }
    }
    #pragma unroll
    for (int q = 0; q < 4; ++q) {
      const float r = 1.f / (1.f + __expf(-ar[q]));
      rhs[q][t] = r * hs[q][t];
    }
  }
  __syncthreads();
  {  // u gate + epilogue
    float au[4] = {0.f, 0.f, 0.f, 0.f};
    const float* wh = Whh + t * 256;
    for (int k = 0; k < 256; k += 4) {
      float4 a = *(const float4*)(wh + k);
      #pragma unroll
      for (int q = 0; q < 4; ++q) {
        const float* hp = &rhs[q][k];
        au[q] = fmaf(a.x, hp[0], fmaf(a.y, hp[1], fmaf(a.z, hp[2], fmaf(a.w, hp[3], au[q]))));
      }
    }
    #pragma unroll
    for (int q = 0; q < 4; ++q) {
      const float z = 1.f / (1.f + __expf(-(az[q] + hzs[q][t])));
      const float u = tanhf(au[q]);
      out[(b0 + q) * 256 + t] = (1.f - z) * (u - hs[q][t]);
    }
  }
}

extern "C" void kernel_launch(void* const* d_in, const int* in_sizes, int n_in,
                              void* d_out, int out_size, void* d_ws, size_t ws_size,
                              hipStream_t stream) {
  const float* h   = (const float*)d_in[1];
  const float* Whr = (const float*)d_in[2];
  const float* Whz = (const float*)d_in[3];
  const float* Whh = (const float*)d_in[4];
  const float* Wf  = (const float*)d_in[5];
  float* out = (float*)d_out;
  char* ws = (char*)d_ws;

  f16* hh   = (f16*)(ws);                            // 512 KiB
  f16* W2t  = (f16*)(ws + (1u << 19));               // 32 MiB
  f16* part = (f16*)(ws + (1u << 19) + (1u << 25));  // 32 MiB (64 x 1024 x 256)

  k_convert<<<dim3(16640), dim3(256), 0, stream>>>(Wf, h, W2t, hh);
  k_gemm<<<dim3(256), dim3(512), 0, stream>>>(hh, W2t, part);
  k_post<<<dim3(256), dim3(256), 0, stream>>>(h, Whr, Whz, Whh, part, out);
}